// Round 14
// baseline (107.693 us; speedup 1.0000x reference)
//
#include <hip/hip_runtime.h>
#include <math.h>

#define B_N 512
#define D_N 768
#define R_N 128
#define ALPHA 2.0f
#define BETA 50.0f
#define BASE 0.5f
#define EPS_M 0.1f
#define NB 8

typedef __attribute__((ext_vector_type(4))) float f32x4;
typedef __attribute__((ext_vector_type(8))) short s16x8;

static __device__ inline unsigned short f2bf(float f) {
    union { float f; unsigned u; } v; v.f = f;
    unsigned u = v.u;
    return (unsigned short)((u + 0x7FFFu + ((u >> 16) & 1u)) >> 16);  // RNE
}

// ---------------- Kernel 1: grouped matvec t[b] = M[re_id[b]] @ x[b] --------
// grid (128, 25), XCD-locality remap (r12 proven). y'<24 = matvec tiles,
// storing t as RAW bf16 + accumulating per-row sumsq via 1 f32 atomic per
// wave per member; y'==24 = cui1 stripe: raw bf16 copy + cinv[512].
__global__ __launch_bounds__(256, 3) void k_matvec(
    const float* __restrict__ transform, const float* __restrict__ cui0,
    const int* __restrict__ re_id, unsigned short* __restrict__ tn,
    float* __restrict__ norm_acc, const float* __restrict__ cui1,
    unsigned short* __restrict__ cn, float* __restrict__ cinv) {
    int tid = threadIdx.x;
    int lane = tid & 63;
    int w = tid >> 6;

    // ---- XCD-locality remap (bijective: 3200 = 8 xcd * 16 r * 25 y) ----
    int linear = blockIdx.y * 128 + blockIdx.x;
    int xcd = linear & 7;
    int idx = linear >> 3;       // 0..399 within this XCD
    int rloc = idx / 25;         // 0..15
    int ytile = idx - rloc * 25; // 0..24
    int r = xcd * 16 + rloc;     // relation (also stripe id when ytile==24)

    if (ytile == 24) {  // ---- cui1 stripe: raw bf16 copy + inv-norm ----
        int gw = r * 4 + w;
        const float4* s4 = (const float4*)(cui1 + (size_t)gw * D_N);
        float4 v[3];
        float ss = 0.f;
#pragma unroll
        for (int c = 0; c < 3; ++c) {
            v[c] = s4[c * 64 + lane];
            ss += v[c].x * v[c].x + v[c].y * v[c].y + v[c].z * v[c].z + v[c].w * v[c].w;
        }
#pragma unroll
        for (int off = 32; off > 0; off >>= 1) ss += __shfl_xor(ss, off, 64);
        ushort4* d4 = (ushort4*)(cn + (size_t)gw * D_N);
#pragma unroll
        for (int c = 0; c < 3; ++c) {
            ushort4 o;
            o.x = f2bf(v[c].x); o.y = f2bf(v[c].y);
            o.z = f2bf(v[c].z); o.w = f2bf(v[c].w);
            d4[c * 64 + lane] = o;
        }
        if (lane == 0) cinv[gw] = 1.0f / fmaxf(sqrtf(ss), 1e-12f);
        return;
    }

    int tile = ytile * 32;
    int g = lane >> 4;    // which of 4 rows in a unit
    int l16 = lane & 15;  // k-slot within the row

    const float* Mbase = transform + (size_t)r * ((size_t)D_N * D_N);
    int i0 = tile + w * 8 + g;
    int i1 = i0 + 4;
    const float4* M0 = (const float4*)(Mbase + (size_t)i0 * D_N);
    const float4* M1 = (const float4*)(Mbase + (size_t)i1 * D_N);
    float4 m0[12], m1[12];
#pragma unroll
    for (int c = 0; c < 12; ++c) m0[c] = M0[l16 + 16 * c];
#pragma unroll
    for (int c = 0; c < 12; ++c) m1[c] = M1[l16 + 16 * c];

    __shared__ int mem_s[B_N];
    __shared__ int cnt_s;
    __shared__ float xs[NB][D_N];  // 24 KiB

    if (tid == 0) cnt_s = 0;
    __syncthreads();
    {
        int a = re_id[tid], b = re_id[tid + 256];
        if (a == r) { int k = atomicAdd(&cnt_s, 1); mem_s[k] = tid; }
        if (b == r) { int k = atomicAdd(&cnt_s, 1); mem_s[k] = tid + 256; }
    }
    __syncthreads();
    int n = cnt_s;
    if (n == 0) return;

    for (int cs = 0; cs < n; cs += NB) {
        int nc = min(NB, n - cs);
        __syncthreads();  // previous chunk done before overwrite
        for (int idx2 = tid; idx2 < nc * 192; idx2 += 256) {
            int cb = idx2 / 192, pos = idx2 - cb * 192;
            int b = mem_s[cs + cb];
            ((float4*)xs[cb])[pos] = ((const float4*)(cui0 + (size_t)b * D_N))[pos];
        }
        __syncthreads();

        for (int cb = 0; cb < nc; ++cb) {
            const float4* xr = (const float4*)xs[cb];
            float a0 = 0.f, a1 = 0.f;
#pragma unroll
            for (int c = 0; c < 12; ++c) {
                float4 x = xr[l16 + 16 * c];
                a0 += m0[c].x * x.x + m0[c].y * x.y + m0[c].z * x.z + m0[c].w * x.w;
                a1 += m1[c].x * x.x + m1[c].y * x.y + m1[c].z * x.z + m1[c].w * x.w;
            }
            a0 += __shfl_xor(a0, 8, 64);
            a1 += __shfl_xor(a1, 8, 64);
            a0 += __shfl_xor(a0, 4, 64);
            a1 += __shfl_xor(a1, 4, 64);
            a0 += __shfl_xor(a0, 2, 64);
            a1 += __shfl_xor(a1, 2, 64);
            a0 += __shfl_xor(a0, 1, 64);
            a1 += __shfl_xor(a1, 1, 64);
            // all 16 lanes of each g-group now hold (a0,a1) for rows (i0,i1)
            int bmem = mem_s[cs + cb];
            if (l16 == 0) {
                size_t ob = (size_t)bmem * D_N;
                tn[ob + i0] = f2bf(a0);
                tn[ob + i1] = f2bf(a1);
            }
            // per-row sumsq partial: reduce a0^2+a1^2 across the 4 g-groups
            float p = a0 * a0 + a1 * a1;
            p += __shfl_xor(p, 16, 64);
            p += __shfl_xor(p, 32, 64);
            if (lane == 0) atomicAdd(&norm_acc[bmem], p);
        }
    }
}

// ---------------- Kernel 2: bf16 MFMA gemm, deferred-norm epilogue ---------
// grid (16,16), block 256 (4 waves). Fragments straight from global bf16;
// epilogue scales by rsqrt(norm_acc[row]) * cinv[col].
__global__ __launch_bounds__(256) void k_gemm(
    const unsigned short* __restrict__ tn, const unsigned short* __restrict__ cn,
    const float* __restrict__ norm_acc, const float* __restrict__ cinv,
    float* __restrict__ mat) {
    int tid = threadIdx.x;
    int lane = tid & 63, w = tid >> 6;
    int wr = w >> 1, wc = w & 1;
    int l15 = lane & 15, lh = lane >> 4;

    int arow = blockIdx.y * 32 + wr * 16 + l15;
    int bcol = blockIdx.x * 32 + wc * 16 + l15;
    const s16x8* ap = (const s16x8*)(tn + (size_t)arow * D_N);
    const s16x8* bp = (const s16x8*)(cn + (size_t)bcol * D_N);

    f32x4 acc0 = {0.f, 0.f, 0.f, 0.f};
    f32x4 acc1 = {0.f, 0.f, 0.f, 0.f};
#pragma unroll
    for (int ks = 0; ks < 24; ks += 2) {
        s16x8 a0 = ap[ks * 4 + lh];
        s16x8 b0 = bp[ks * 4 + lh];
        s16x8 a1 = ap[ks * 4 + 4 + lh];
        s16x8 b1 = bp[ks * 4 + 4 + lh];
        acc0 = __builtin_amdgcn_mfma_f32_16x16x32_bf16(a0, b0, acc0, 0, 0, 0);
        acc1 = __builtin_amdgcn_mfma_f32_16x16x32_bf16(a1, b1, acc1, 0, 0, 0);
    }

    // C/D layout col=lane&15, row=(lane>>4)*4+reg  [m89; HW-verified]
    float ic = cinv[bcol];
    int grow = blockIdx.y * 32 + wr * 16 + lh * 4;
#pragma unroll
    for (int p = 0; p < 4; ++p) {
        float it = 1.0f / fmaxf(sqrtf(norm_acc[grow + p]), 1e-12f);
        mat[(size_t)(grow + p) * B_N + bcol] = (acc0[p] + acc1[p]) * it * ic;
    }
}

// ---------------- Kernel 3: miner + MS loss per row, fused mean ----------
__global__ __launch_bounds__(256) void k_loss(
    const float* __restrict__ mat, const int* __restrict__ lab,
    float* __restrict__ row_loss, int* __restrict__ sync_cnt,
    float* __restrict__ out) {
    int r = blockIdx.x;
    int tid = threadIdx.x;
    int lane = tid & 63, w = tid >> 6;
    __shared__ float tmp[4];
    __shared__ int is_last;
    int lr = lab[r];
    const float* mrow = mat + (size_t)r * B_N;

    float v0 = mrow[tid], v1 = mrow[tid + 256];
    bool m0 = (lab[tid] == lr), m1 = (lab[tid + 256] == lr);

    float mx = -INFINITY, mn = INFINITY;
    if (m0) mn = v0; else mx = v0;
    if (m1) mn = fminf(mn, v1); else mx = fmaxf(mx, v1);

#pragma unroll
    for (int off = 32; off > 0; off >>= 1) mx = fmaxf(mx, __shfl_xor(mx, off, 64));
    if (lane == 0) tmp[w] = mx;
    __syncthreads();
    float max_neg = fmaxf(fmaxf(tmp[0], tmp[1]), fmaxf(tmp[2], tmp[3]));
    __syncthreads();

#pragma unroll
    for (int off = 32; off > 0; off >>= 1) mn = fminf(mn, __shfl_xor(mn, off, 64));
    if (lane == 0) tmp[w] = mn;
    __syncthreads();
    float min_pos = fminf(fminf(tmp[0], tmp[1]), fminf(tmp[2], tmp[3]));
    __syncthreads();

    float psum = 0.f, nsum = 0.f;
    if (m0 && (v0 - EPS_M < max_neg)) psum += expf(ALPHA * (BASE - v0));
    if (!m0 && (v0 + EPS_M > min_pos)) nsum += expf(BETA * (v0 - BASE));
    if (m1 && (v1 - EPS_M < max_neg)) psum += expf(ALPHA * (BASE - v1));
    if (!m1 && (v1 + EPS_M > min_pos)) nsum += expf(BETA * (v1 - BASE));

#pragma unroll
    for (int off = 32; off > 0; off >>= 1) psum += __shfl_xor(psum, off, 64);
    if (lane == 0) tmp[w] = psum;
    __syncthreads();
    float ps = tmp[0] + tmp[1] + tmp[2] + tmp[3];
    __syncthreads();

#pragma unroll
    for (int off = 32; off > 0; off >>= 1) nsum += __shfl_xor(nsum, off, 64);
    if (lane == 0) tmp[w] = nsum;
    __syncthreads();
    float ns = tmp[0] + tmp[1] + tmp[2] + tmp[3];

    if (tid == 0) {
        row_loss[r] = (1.0f / ALPHA) * log1pf(ps) + (1.0f / BETA) * log1pf(ns);
        __threadfence();
        int prev = atomicAdd(sync_cnt, 1);
        is_last = (prev == B_N - 1) ? 1 : 0;
    }
    __syncthreads();
    if (is_last) {
        __threadfence();
        float v = row_loss[tid] + row_loss[tid + 256];
#pragma unroll
        for (int off = 32; off > 0; off >>= 1) v += __shfl_xor(v, off, 64);
        if (lane == 0) tmp[w] = v;
        __syncthreads();
        if (tid == 0)
            out[0] = (tmp[0] + tmp[1] + tmp[2] + tmp[3]) / (float)B_N;
    }
}

extern "C" void kernel_launch(void* const* d_in, const int* in_sizes, int n_in,
                              void* d_out, int out_size, void* d_ws, size_t ws_size,
                              hipStream_t stream) {
    const float* cui0      = (const float*)d_in[0];
    const float* cui1      = (const float*)d_in[1];
    const int*   re_id     = (const int*)d_in[2];
    const int*   lab1      = (const int*)d_in[4];
    const float* transform = (const float*)d_in[5];
    float* out = (float*)d_out;

    char* wsb = (char*)d_ws;
    unsigned short* tn = (unsigned short*)wsb;              // 512*768 bf16 (raw t)
    unsigned short* cn = (unsigned short*)(wsb + 786432);   // 512*768 bf16 (raw cui1)
    float* mat      = (float*)(wsb + 1572864);              // 512*512 f32 (cosine)
    float* row_loss = (float*)(wsb + 2621440);              // 512 f32
    float* norm_acc = (float*)(wsb + 2623488);              // 512 f32 (zeroed)
    int*   scnt     = (int*)(wsb + 2625536);                // 1 (zeroed)
    float* cinv     = (float*)(wsb + 2625552);              // 512 f32

    // zero norm_acc + scnt (graph-capture-safe async memset)
    hipMemsetAsync(wsb + 2623488, 0, 2048 + 16, stream);

    hipLaunchKernelGGL(k_matvec, dim3(R_N, 25), dim3(256), 0, stream,
                       transform, cui0, re_id, tn, norm_acc, cui1, cn, cinv);
    hipLaunchKernelGGL(k_gemm, dim3(16, 16), dim3(256), 0, stream,
                       tn, cn, norm_acc, cinv, mat);
    hipLaunchKernelGGL(k_loss, dim3(B_N), dim3(256), 0, stream,
                       mat, lab1, row_loss, scnt, out);
}

// Round 15
// 79.854 us; speedup vs baseline: 1.3486x; 1.3486x over previous
//
#include <hip/hip_runtime.h>
#include <math.h>

#define B_N 512
#define D_N 768
#define R_N 128
#define ALPHA 2.0f
#define BETA 50.0f
#define BASE 0.5f
#define EPS_M 0.1f
#define NB 8

typedef __attribute__((ext_vector_type(4))) float f32x4;
typedef __attribute__((ext_vector_type(8))) short s16x8;

static __device__ inline unsigned short f2bf(float f) {
    union { float f; unsigned u; } v; v.f = f;
    unsigned u = v.u;
    return (unsigned short)((u + 0x7FFFu + ((u >> 16) & 1u)) >> 16);  // RNE
}

// ---------------- Kernel 1: grouped matvec t[b] = M[re_id[b]] @ x[b] --------
// grid (128, 25) remapped so all 25 blocks of one relation run on one XCD:
// linear%8 = hardware XCD; XCD k owns relations [16k,16k+16). Members' cui0
// rows + re_id then stay L2-resident per XCD (x traffic -23/24).
// y'<24 = matvec tiles (r6 structure); y'==24 = cui1-norm stripe.
__global__ __launch_bounds__(256, 3) void k_matvec(
    const float* __restrict__ transform, const float* __restrict__ cui0,
    const int* __restrict__ re_id, float* __restrict__ t_out,
    const float* __restrict__ cui1, unsigned short* __restrict__ cn) {
    int tid = threadIdx.x;
    int lane = tid & 63;
    int w = tid >> 6;

    // ---- XCD-locality remap (bijective: 3200 = 8 xcd * 16 r * 25 y) ----
    int linear = blockIdx.y * 128 + blockIdx.x;
    int xcd = linear & 7;
    int idx = linear >> 3;       // 0..399 within this XCD
    int rloc = idx / 25;         // 0..15
    int ytile = idx - rloc * 25; // 0..24
    int r = xcd * 16 + rloc;     // relation (also stripe id when ytile==24)

    if (ytile == 24) {  // ---- cui1 norm stripe: 4 rows per block ----
        int gw = r * 4 + w;
        const float4* s4 = (const float4*)(cui1 + (size_t)gw * D_N);
        float4 v[3];
        float ss = 0.f;
#pragma unroll
        for (int c = 0; c < 3; ++c) {
            v[c] = s4[c * 64 + lane];
            ss += v[c].x * v[c].x + v[c].y * v[c].y + v[c].z * v[c].z + v[c].w * v[c].w;
        }
#pragma unroll
        for (int off = 32; off > 0; off >>= 1) ss += __shfl_xor(ss, off, 64);
        float inv = 1.0f / fmaxf(sqrtf(ss), 1e-12f);
        ushort4* d4 = (ushort4*)(cn + (size_t)gw * D_N);
#pragma unroll
        for (int c = 0; c < 3; ++c) {
            ushort4 o;
            o.x = f2bf(v[c].x * inv); o.y = f2bf(v[c].y * inv);
            o.z = f2bf(v[c].z * inv); o.w = f2bf(v[c].w * inv);
            d4[c * 64 + lane] = o;
        }
        return;
    }

    int tile = ytile * 32;
    int g = lane >> 4;    // which of 4 rows in a unit
    int l16 = lane & 15;  // k-slot within the row

    const float* Mbase = transform + (size_t)r * ((size_t)D_N * D_N);
    int i0 = tile + w * 8 + g;
    int i1 = i0 + 4;
    const float4* M0 = (const float4*)(Mbase + (size_t)i0 * D_N);
    const float4* M1 = (const float4*)(Mbase + (size_t)i1 * D_N);
    float4 m0[12], m1[12];
#pragma unroll
    for (int c = 0; c < 12; ++c) m0[c] = M0[l16 + 16 * c];
#pragma unroll
    for (int c = 0; c < 12; ++c) m1[c] = M1[l16 + 16 * c];

    __shared__ int mem_s[B_N];
    __shared__ int cnt_s;
    __shared__ float xs[NB][D_N];  // 24 KiB

    if (tid == 0) cnt_s = 0;
    __syncthreads();
    {
        int a = re_id[tid], b = re_id[tid + 256];
        if (a == r) { int k = atomicAdd(&cnt_s, 1); mem_s[k] = tid; }
        if (b == r) { int k = atomicAdd(&cnt_s, 1); mem_s[k] = tid + 256; }
    }
    __syncthreads();
    int n = cnt_s;
    if (n == 0) return;

    for (int cs = 0; cs < n; cs += NB) {
        int nc = min(NB, n - cs);
        __syncthreads();  // previous chunk done before overwrite
        for (int idx2 = tid; idx2 < nc * 192; idx2 += 256) {
            int cb = idx2 / 192, pos = idx2 - cb * 192;
            int b = mem_s[cs + cb];
            ((float4*)xs[cb])[pos] = ((const float4*)(cui0 + (size_t)b * D_N))[pos];
        }
        __syncthreads();

        for (int cb = 0; cb < nc; ++cb) {
            const float4* xr = (const float4*)xs[cb];
            float a0 = 0.f, a1 = 0.f;
#pragma unroll
            for (int c = 0; c < 12; ++c) {
                float4 x = xr[l16 + 16 * c];
                a0 += m0[c].x * x.x + m0[c].y * x.y + m0[c].z * x.z + m0[c].w * x.w;
                a1 += m1[c].x * x.x + m1[c].y * x.y + m1[c].z * x.z + m1[c].w * x.w;
            }
            a0 += __shfl_xor(a0, 8, 64);
            a1 += __shfl_xor(a1, 8, 64);
            a0 += __shfl_xor(a0, 4, 64);
            a1 += __shfl_xor(a1, 4, 64);
            a0 += __shfl_xor(a0, 2, 64);
            a1 += __shfl_xor(a1, 2, 64);
            a0 += __shfl_xor(a0, 1, 64);
            a1 += __shfl_xor(a1, 1, 64);
            if (l16 == 0) {
                size_t ob = (size_t)mem_s[cs + cb] * D_N;
                t_out[ob + i0] = a0;
                t_out[ob + i1] = a1;
            }
        }
    }
}

// ---------------- Kernel 2: t norms -> normalized bf16 copy ----------------
// grid 128, block 256 (4 waves); one wave per row, 512 t rows (L2-hot).
__global__ __launch_bounds__(256) void k_normbf16(
    const float* __restrict__ t_in, unsigned short* __restrict__ tn,
    int* __restrict__ scnt) {
    if (blockIdx.x == 0 && threadIdx.x == 0) *scnt = 0;
    int gw = blockIdx.x * 4 + (threadIdx.x >> 6);
    int lane = threadIdx.x & 63;
    const float4* s4 = (const float4*)(t_in + (size_t)gw * D_N);
    float4 v[3];
    float ss = 0.f;
#pragma unroll
    for (int c = 0; c < 3; ++c) {
        v[c] = s4[c * 64 + lane];
        ss += v[c].x * v[c].x + v[c].y * v[c].y + v[c].z * v[c].z + v[c].w * v[c].w;
    }
#pragma unroll
    for (int off = 32; off > 0; off >>= 1) ss += __shfl_xor(ss, off, 64);
    float inv = 1.0f / fmaxf(sqrtf(ss), 1e-12f);
    ushort4* d4 = (ushort4*)(tn + (size_t)gw * D_N);
#pragma unroll
    for (int c = 0; c < 3; ++c) {
        ushort4 o;
        o.x = f2bf(v[c].x * inv); o.y = f2bf(v[c].y * inv);
        o.z = f2bf(v[c].z * inv); o.w = f2bf(v[c].w * inv);
        d4[c * 64 + lane] = o;
    }
}

// ---------------- Kernel 3: LDS-free bf16 MFMA gemm  mat = Tn @ Cn^T -------
// grid (16,16), block 256 (4 waves). Fragments straight from global bf16.
__global__ __launch_bounds__(256) void k_gemm(
    const unsigned short* __restrict__ tn, const unsigned short* __restrict__ cn,
    float* __restrict__ mat) {
    int tid = threadIdx.x;
    int lane = tid & 63, w = tid >> 6;
    int wr = w >> 1, wc = w & 1;
    int l15 = lane & 15, lh = lane >> 4;

    int arow = blockIdx.y * 32 + wr * 16 + l15;
    int bcol = blockIdx.x * 32 + wc * 16 + l15;
    const s16x8* ap = (const s16x8*)(tn + (size_t)arow * D_N);
    const s16x8* bp = (const s16x8*)(cn + (size_t)bcol * D_N);

    f32x4 acc0 = {0.f, 0.f, 0.f, 0.f};
    f32x4 acc1 = {0.f, 0.f, 0.f, 0.f};
#pragma unroll
    for (int ks = 0; ks < 24; ks += 2) {
        s16x8 a0 = ap[ks * 4 + lh];
        s16x8 b0 = bp[ks * 4 + lh];
        s16x8 a1 = ap[ks * 4 + 4 + lh];
        s16x8 b1 = bp[ks * 4 + 4 + lh];
        acc0 = __builtin_amdgcn_mfma_f32_16x16x32_bf16(a0, b0, acc0, 0, 0, 0);
        acc1 = __builtin_amdgcn_mfma_f32_16x16x32_bf16(a1, b1, acc1, 0, 0, 0);
    }

    // C/D layout col=lane&15, row=(lane>>4)*4+reg  [m89; HW-verified]
    int grow = blockIdx.y * 32 + wr * 16 + lh * 4;
#pragma unroll
    for (int p = 0; p < 4; ++p)
        mat[(size_t)(grow + p) * B_N + bcol] = acc0[p] + acc1[p];
}

// ---------------- Kernel 4: miner + MS loss per row, fused mean ----------
__global__ __launch_bounds__(256) void k_loss(
    const float* __restrict__ mat, const int* __restrict__ lab,
    float* __restrict__ row_loss, int* __restrict__ sync_cnt,
    float* __restrict__ out) {
    int r = blockIdx.x;
    int tid = threadIdx.x;
    int lane = tid & 63, w = tid >> 6;
    __shared__ float tmp[4];
    __shared__ int is_last;
    int lr = lab[r];
    const float* mrow = mat + (size_t)r * B_N;

    float v0 = mrow[tid], v1 = mrow[tid + 256];
    bool m0 = (lab[tid] == lr), m1 = (lab[tid + 256] == lr);

    float mx = -INFINITY, mn = INFINITY;
    if (m0) mn = v0; else mx = v0;
    if (m1) mn = fminf(mn, v1); else mx = fmaxf(mx, v1);

#pragma unroll
    for (int off = 32; off > 0; off >>= 1) mx = fmaxf(mx, __shfl_xor(mx, off, 64));
    if (lane == 0) tmp[w] = mx;
    __syncthreads();
    float max_neg = fmaxf(fmaxf(tmp[0], tmp[1]), fmaxf(tmp[2], tmp[3]));
    __syncthreads();

#pragma unroll
    for (int off = 32; off > 0; off >>= 1) mn = fminf(mn, __shfl_xor(mn, off, 64));
    if (lane == 0) tmp[w] = mn;
    __syncthreads();
    float min_pos = fminf(fminf(tmp[0], tmp[1]), fminf(tmp[2], tmp[3]));
    __syncthreads();

    float psum = 0.f, nsum = 0.f;
    if (m0 && (v0 - EPS_M < max_neg)) psum += expf(ALPHA * (BASE - v0));
    if (!m0 && (v0 + EPS_M > min_pos)) nsum += expf(BETA * (v0 - BASE));
    if (m1 && (v1 - EPS_M < max_neg)) psum += expf(ALPHA * (BASE - v1));
    if (!m1 && (v1 + EPS_M > min_pos)) nsum += expf(BETA * (v1 - BASE));

#pragma unroll
    for (int off = 32; off > 0; off >>= 1) psum += __shfl_xor(psum, off, 64);
    if (lane == 0) tmp[w] = psum;
    __syncthreads();
    float ps = tmp[0] + tmp[1] + tmp[2] + tmp[3];
    __syncthreads();

#pragma unroll
    for (int off = 32; off > 0; off >>= 1) nsum += __shfl_xor(nsum, off, 64);
    if (lane == 0) tmp[w] = nsum;
    __syncthreads();
    float ns = tmp[0] + tmp[1] + tmp[2] + tmp[3];

    if (tid == 0) {
        row_loss[r] = (1.0f / ALPHA) * log1pf(ps) + (1.0f / BETA) * log1pf(ns);
        __threadfence();
        int prev = atomicAdd(sync_cnt, 1);
        is_last = (prev == B_N - 1) ? 1 : 0;
    }
    __syncthreads();
    if (is_last) {
        __threadfence();
        float v = row_loss[tid] + row_loss[tid + 256];
#pragma unroll
        for (int off = 32; off > 0; off >>= 1) v += __shfl_xor(v, off, 64);
        if (lane == 0) tmp[w] = v;
        __syncthreads();
        if (tid == 0)
            out[0] = (tmp[0] + tmp[1] + tmp[2] + tmp[3]) / (float)B_N;
    }
}

extern "C" void kernel_launch(void* const* d_in, const int* in_sizes, int n_in,
                              void* d_out, int out_size, void* d_ws, size_t ws_size,
                              hipStream_t stream) {
    const float* cui0      = (const float*)d_in[0];
    const float* cui1      = (const float*)d_in[1];
    const int*   re_id     = (const int*)d_in[2];
    const int*   lab1      = (const int*)d_in[4];
    const float* transform = (const float*)d_in[5];
    float* out = (float*)d_out;

    char* wsb = (char*)d_ws;
    unsigned short* tn = (unsigned short*)wsb;              // 512*768 bf16
    unsigned short* cn = (unsigned short*)(wsb + 786432);   // 512*768 bf16
    float* t        = (float*)(wsb + 1572864);              // 512*768 f32
    float* mat      = (float*)(wsb + 3145728);              // 512*512 f32
    float* row_loss = (float*)(wsb + 4194304);              // 512 f32
    int*   scnt     = (int*)(wsb + 4196352);                // 1

    hipLaunchKernelGGL(k_matvec, dim3(R_N, 25), dim3(256), 0, stream,
                       transform, cui0, re_id, t, cui1, cn);
    hipLaunchKernelGGL(k_normbf16, dim3(128), dim3(256), 0, stream,
                       t, tn, scnt);
    hipLaunchKernelGGL(k_gemm, dim3(16, 16), dim3(256), 0, stream,
                       tn, cn, mat);
    hipLaunchKernelGGL(k_loss, dim3(B_N), dim3(256), 0, stream,
                       mat, lab1, row_loss, scnt, out);
}